// Round 13
// baseline (97.147 us; speedup 1.0000x reference)
//
#include <hip/hip_runtime.h>
#include <hip/hip_bf16.h>

#define BB    32
#define LL    8400
#define NGT   64
#define CCH   1
#define KPT   17
#define NTOPK 13
#define POOL  1024
#define NBIN  32           // 32x32 bins over [0,640], bin width 20 -> *0.05f
#define CLRB  68           // clear blocks in prep kernel

// f32-element chunk offsets (return order: labels, bboxes, poses, scores, gt_index)
#define OFF_LAB  ((size_t)0)
#define OFF_BOX  ((size_t)268800)
#define OFF_POSE ((size_t)1344000)
#define OFF_SC   ((size_t)15052800)
#define OFF_GI   ((size_t)15321600)

// workspace layout (bytes)
#define WS_CELLS    0
#define WS_RM       1075200
#define WS_RI       1083392
#define WS_ASSIGNED 1091584
#define WS_BINSTART 2166784     // 1025 ints
#define WS_BINID    2170888     // 8400 ints
#define WS_BINXY    2204488     // 8400 float2, 8B-aligned

// ---------- helpers (fp contract OFF to match the CPU reference op order) ----------

__device__ __forceinline__ float iou_pair(float gx1, float gy1, float gx2, float gy2,
                                          float px1, float py1, float px2, float py2)
{
#pragma clang fp contract(off)
    float ltx = fmaxf(gx1, px1);
    float lty = fmaxf(gy1, py1);
    float rbx = fminf(gx2, px2);
    float rby = fminf(gy2, py2);
    float w = fmaxf(rbx - ltx, 0.0f);
    float h = fmaxf(rby - lty, 0.0f);
    float inter = w * h;
    float ag = (gx2 - gx1) * (gy2 - gy1);
    float ap = (px2 - px1) * (py2 - py1);
    return inter / (ag + ap - inter + 1e-9f);
}

__device__ __forceinline__ bool in_box(float ax, float ay,
                                       float gx1, float gy1, float gx2, float gy2)
{
#pragma clang fp contract(off)
    float m = fminf(fminf(ax - gx1, ay - gy1), fminf(gx2 - ax, gy2 - ay));
    return m > 1e-9f;
}

__device__ __forceinline__ float pow6(float x)
{
#pragma clang fp contract(off)
    float x2 = x * x;
    return (x2 * x2) * x2;
}

__device__ __forceinline__ int bin_of(float x)
{
    int v = (int)floorf(x * 0.05f);        // monotone in x
    return v < 0 ? 0 : (v > NBIN - 1 ? NBIN - 1 : v);
}

// ---------- K_prep: blocks 0..67 clear cells+rowmax; block 68 builds bins ----------

__global__ __launch_bounds__(256) void prep_kernel(
    const float* __restrict__ anchor_points, char* __restrict__ ws)
{
    int tid = threadIdx.x;
    if (blockIdx.x < CLRB) {
        const int N4 = 1091584 / 16;       // 68,224 float4
        for (int t = blockIdx.x * 256 + tid; t < N4; t += CLRB * 256)
            reinterpret_cast<float4*>(ws + WS_CELLS)[t] = make_float4(0.f, 0.f, 0.f, 0.f);
        return;
    }

    // single-block binning: LDS count -> LDS scan -> LDS-cursor scatter
    __shared__ int cnt[NBIN * NBIN];
    __shared__ int scn[NBIN * NBIN];
    __shared__ int tmp[NBIN * NBIN];

    for (int j = tid; j < NBIN * NBIN; j += 256) cnt[j] = 0;
    __syncthreads();
    for (int l = tid; l < LL; l += 256) {
        float2 ap = reinterpret_cast<const float2*>(anchor_points)[l];
        atomicAdd(&cnt[bin_of(ap.y) * NBIN + bin_of(ap.x)], 1);
    }
    __syncthreads();
    for (int j = tid; j < NBIN * NBIN; j += 256) scn[j] = cnt[j];
    __syncthreads();
    for (int s = 1; s < NBIN * NBIN; s <<= 1) {
        for (int j = tid; j < NBIN * NBIN; j += 256)
            tmp[j] = scn[j] + ((j >= s) ? scn[j - s] : 0);
        __syncthreads();
        for (int j = tid; j < NBIN * NBIN; j += 256) scn[j] = tmp[j];
        __syncthreads();
    }
    int* bin_start = (int*)(ws + WS_BINSTART);
    for (int j = tid; j < NBIN * NBIN; j += 256) bin_start[j + 1] = scn[j];
    if (tid == 0) bin_start[0] = 0;
    for (int j = tid; j < NBIN * NBIN; j += 256) cnt[j] = scn[j] - cnt[j];  // excl cursor
    __syncthreads();

    int*    bin_id = (int*)(ws + WS_BINID);
    float2* bin_xy = (float2*)(ws + WS_BINXY);
    for (int l = tid; l < LL; l += 256) {
        float2 ap = reinterpret_cast<const float2*>(anchor_points)[l];
        int bin = bin_of(ap.y) * NBIN + bin_of(ap.x);
        int slot = atomicAdd(&cnt[bin], 1);
        bin_id[slot] = l;
        bin_xy[slot] = ap;
    }
}

// ---------- K1: single-wave binned candidate-pool exact top-13 ----------
// key = (value_bits << 32) | (0xFFFFFFFF - l)  -> order = (value desc, index asc),
// exactly lax.top_k's tie semantics; keys unique. Pool = {in-box anchors, full
// metric} U {l<26 out-of-box, v=0}: provably contains the reference's top-13.

__global__ __launch_bounds__(64) void topk_kernel(
    const float* __restrict__ pred_scores,
    const float* __restrict__ pred_bboxes,
    const float* __restrict__ anchor_points,
    const int*   __restrict__ gt_labels,
    const float* __restrict__ gt_bboxes,
    const float* __restrict__ pad_gt_mask,
    const int*   __restrict__ bin_start,
    const int*   __restrict__ bin_id,
    const float2* __restrict__ bin_xy,
    unsigned*    __restrict__ cells)
{
    __shared__ unsigned long long pool[POOL];          // 8,192 B
    __shared__ int cnt;

    int b = blockIdx.x >> 6;
    int i = blockIdx.x & 63;
    if (pad_gt_mask[b * NGT + i] == 0.0f) return;   // padded row (uniform exit)

    int lane = threadIdx.x;
    if (lane == 0) cnt = 0;
    __syncthreads();

    int gbase = (b * NGT + i) * 4;
    float gx1 = gt_bboxes[gbase + 0];
    float gy1 = gt_bboxes[gbase + 1];
    float gx2 = gt_bboxes[gbase + 2];
    float gy2 = gt_bboxes[gbase + 3];
    int lbl = gt_labels[b * NGT + i];

    // pre-pass: zero-metric fallback candidates l<26 (out-of-box only)
    if (lane < 2 * NTOPK) {
        float2 ap = reinterpret_cast<const float2*>(anchor_points)[lane];
        if (!in_box(ap.x, ap.y, gx1, gy1, gx2, gy2)) {
            int slot = atomicAdd(&cnt, 1);
            pool[slot] = (unsigned long long)(0xFFFFFFFFu - (unsigned)lane);  // v=0
        }
    }

    // bin-rect scan: per by-row, bins bx0..bx1 form one contiguous slot range
    int bx0 = bin_of(gx1), bx1 = bin_of(gx2);
    int by0 = bin_of(gy1), by1 = bin_of(gy2);
    for (int by = by0; by <= by1; ++by) {
        int s = bin_start[by * NBIN + bx0];
        int e = bin_start[by * NBIN + bx1 + 1];
        for (int t = s + lane; t < e; t += 64) {
            float2 ap = bin_xy[t];
            if (in_box(ap.x, ap.y, gx1, gy1, gx2, gy2)) {
                int l = bin_id[t];
                int pidx = b * LL + l;
                float4 pb = reinterpret_cast<const float4*>(pred_bboxes)[pidx];
                float iou = iou_pair(gx1, gy1, gx2, gy2, pb.x, pb.y, pb.z, pb.w);
                float score = pred_scores[pidx * CCH + lbl];
                float v = score * pow6(iou);            // >= 0
                int slot = atomicAdd(&cnt, 1);
                if (slot < POOL) {
                    pool[slot] =
                        ((unsigned long long)__float_as_uint(v) << 32) |
                        (unsigned long long)(0xFFFFFFFFu - (unsigned)l);
                }
            }
        }
    }
    __syncthreads();

    int total = cnt;
    unsigned long long winner = 0;         // lane k holds round-k winner
    if (total <= POOL) {
#pragma unroll
        for (int k = 0; k < NTOPK; ++k) {
            unsigned long long lm = 0;
            int li = -1;
            for (int e = lane; e < total; e += 64) {
                unsigned long long pv = pool[e];
                if (pv > lm) { lm = pv; li = e; }
            }
            unsigned long long m = lm;
#pragma unroll
            for (int off = 32; off > 0; off >>= 1) {
                unsigned long long o = __shfl_xor(m, off);
                m = o > m ? o : m;
            }
            if (lane == k) winner = m;
            if (li >= 0 && lm == m) pool[li] = 0;   // consume (unique key -> one lane)
        }
    } else {
        // overflow fallback (unreachable on this data): threshold-descend full rescan
        unsigned long long prev = ~0ull;
#pragma unroll 1
        for (int k = 0; k < NTOPK; ++k) {
            unsigned long long lm = 0;
            for (int l = lane; l < LL; l += 64) {
                int pidx = b * LL + l;
                float4 pb = reinterpret_cast<const float4*>(pred_bboxes)[pidx];
                float iou = iou_pair(gx1, gy1, gx2, gy2, pb.x, pb.y, pb.z, pb.w);
                float score = pred_scores[pidx * CCH + lbl];
                float metric = score * pow6(iou);
                float2 ap = reinterpret_cast<const float2*>(anchor_points)[l];
                float v = in_box(ap.x, ap.y, gx1, gy1, gx2, gy2) ? metric : 0.0f;
                unsigned long long key =
                    ((unsigned long long)__float_as_uint(v) << 32) |
                    (unsigned long long)(0xFFFFFFFFu - (unsigned)l);
                if (key < prev && key > lm) lm = key;
            }
            unsigned long long m = lm;
#pragma unroll
            for (int off = 32; off > 0; off >>= 1) {
                unsigned long long o = __shfl_xor(m, off);
                m = o > m ? o : m;
            }
            if (lane == k) winner = m;
            prev = m;
        }
    }

    // parallel emit: lanes 0..12 process their winner concurrently
    if (lane < NTOPK && winner != 0ull) {
        unsigned lw = 0xFFFFFFFFu - (unsigned)(winner & 0xFFFFFFFFull);
        float v = __uint_as_float((unsigned)(winner >> 32));
        bool posw;
        if (v > 0.0f) {
            posw = true;                   // metric>0 implies in_gts
        } else {
            float2 ap = reinterpret_cast<const float2*>(anchor_points)[lw];
            posw = in_box(ap.x, ap.y, gx1, gy1, gx2, gy2);
        }
        if (posw)
            atomicAdd(&cells[b * LL + lw], 1u + ((unsigned)i << 8));
    }
}

// ---------- K2: decode cell -> assigned gt (or -1) + row maxima of metric/iou ----------

__global__ __launch_bounds__(256) void decode_kernel(
    const float* __restrict__ pred_scores,
    const float* __restrict__ pred_bboxes,
    const int*   __restrict__ gt_labels,
    const float* __restrict__ gt_bboxes,
    const unsigned* __restrict__ cells,
    int*      __restrict__ assigned,
    unsigned* __restrict__ rowmax_metric,
    unsigned* __restrict__ rowmax_iou)
{
    __shared__ float gsh[NGT * 4];
    int b = blockIdx.y;
    int tid = threadIdx.x;
    for (int k = tid; k < NGT * 4; k += 256) gsh[k] = gt_bboxes[b * NGT * 4 + k];
    __syncthreads();

    int l = blockIdx.x * 256 + tid;
    if (l >= LL) return;
    int idx = b * LL + l;

    unsigned cell = cells[idx];
    int cnt = (int)(cell & 0xFFu);
    if (cnt == 0) { assigned[idx] = -1; return; }

    float px1 = pred_bboxes[idx * 4 + 0];
    float py1 = pred_bboxes[idx * 4 + 1];
    float px2 = pred_bboxes[idx * 4 + 2];
    float py2 = pred_bboxes[idx * 4 + 3];

    int istar;
    if (cnt == 1) {
        int v = (int)(cell >> 8);
        istar = (v >= 0 && v < NGT) ? v : 0;
    } else {
        // reference substitutes is_max_iou over ALL 64 gts (incl. padded), first-max tie
        float best = -1.0f;
        int bi = 0;
        for (int i = 0; i < NGT; ++i) {
            float iou = iou_pair(gsh[i * 4 + 0], gsh[i * 4 + 1], gsh[i * 4 + 2], gsh[i * 4 + 3],
                                 px1, py1, px2, py2);
            if (iou > best) { best = iou; bi = i; }
        }
        istar = bi;
    }
    assigned[idx] = istar;

    float iou = iou_pair(gsh[istar * 4 + 0], gsh[istar * 4 + 1], gsh[istar * 4 + 2], gsh[istar * 4 + 3],
                         px1, py1, px2, py2);
    int lbl = gt_labels[b * NGT + istar];
    float score = pred_scores[idx * CCH + lbl];
    float met = score * pow6(iou);
    atomicMax(&rowmax_metric[b * NGT + istar], __float_as_uint(met));  // values >= 0
    atomicMax(&rowmax_iou[b * NGT + istar], __float_as_uint(iou));
}

// ---------- K3: fused writer — blocks <1056: labels/bbox/scores/gi; rest: poses ----------

__global__ __launch_bounds__(256) void write_pose_kernel(
    const float* __restrict__ pred_scores,
    const float* __restrict__ pred_bboxes,
    const int*   __restrict__ gt_labels,
    const float* __restrict__ gt_bboxes,
    const float* __restrict__ gt_poses,
    const int*      __restrict__ assigned,
    const unsigned* __restrict__ rowmax_metric,
    const unsigned* __restrict__ rowmax_iou,
    const int*   __restrict__ bg_ptr,
    float* __restrict__ out)
{
    __shared__ float gsh[NGT * 4];
    int blk = blockIdx.x;
    int tid = threadIdx.x;

    if (blk < 1056) {
        int b = blk / 33;
        int lb = blk - b * 33;
        for (int k = tid; k < NGT * 4; k += 256) gsh[k] = gt_bboxes[b * NGT * 4 + k];
        __syncthreads();

        int l = lb * 256 + tid;
        if (l >= LL) return;
        int idx = b * LL + l;

        int a = assigned[idx];
        bool pos = a >= 0;
        int agi = pos ? a : 0;             // argmax of all-zero column == 0
        int bg = *bg_ptr;
        int lbl = pos ? gt_labels[b * NGT + agi] : bg;

        out[OFF_LAB + (size_t)idx] = (float)lbl;
        out[OFF_GI + (size_t)idx]  = (float)(b * NGT + agi);

        float4 box;
        box.x = gsh[agi * 4 + 0];
        box.y = gsh[agi * 4 + 1];
        box.z = gsh[agi * 4 + 2];
        box.w = gsh[agi * 4 + 3];
        reinterpret_cast<float4*>(out + OFF_BOX)[idx] = box;

        float am = 0.0f;
        if (pos) {
            float px1 = pred_bboxes[idx * 4 + 0];
            float py1 = pred_bboxes[idx * 4 + 1];
            float px2 = pred_bboxes[idx * 4 + 2];
            float py2 = pred_bboxes[idx * 4 + 3];
            float iou = iou_pair(box.x, box.y, box.z, box.w, px1, py1, px2, py2);
            float score = pred_scores[idx * CCH + gt_labels[b * NGT + a]];
            float met = score * pow6(iou);
            float mm = __uint_as_float(rowmax_metric[b * NGT + a]);
            float mi = __uint_as_float(rowmax_iou[b * NGT + a]);
            am = met / (mm + 1e-9f) * mi;
        }
        int kc = (bg == 0) ? 1 : 0;        // kept class column (C==1)
        out[OFF_SC + (size_t)idx] = (lbl == kc) ? am : 0.0f;
    } else {
        const int TOT4 = BB * LL * KPT * 3 / 4;     // 3,427,200
        int c = (blk - 1056) * 256 + tid;
        if (c >= TOT4) return;
        int e0 = c * 4;
        float r[4];
#pragma unroll
        for (int u = 0; u < 4; ++u) {
            int e = e0 + u;
            int anchor = e / (KPT * 3);             // const-div -> magic mul
            int j = e - anchor * (KPT * 3);
            int b = anchor / LL;
            int a = assigned[anchor];
            int agi = a >= 0 ? a : 0;
            r[u] = gt_poses[(size_t)(b * NGT + agi) * (KPT * 3) + j];
        }
        float4 v;
        v.x = r[0]; v.y = r[1]; v.z = r[2]; v.w = r[3];
        reinterpret_cast<float4*>(out + OFF_POSE)[c] = v;   // 16B-aligned
    }
}

// ---------- launch: 4 dispatches total ----------

extern "C" void kernel_launch(void* const* d_in, const int* in_sizes, int n_in,
                              void* d_out, int out_size, void* d_ws, size_t ws_size,
                              hipStream_t stream)
{
    const float* pred_scores   = (const float*)d_in[0];
    const float* pred_bboxes   = (const float*)d_in[1];
    // d_in[2] = pred_poses: unused by the reference computation
    const float* anchor_points = (const float*)d_in[3];
    const int*   gt_labels     = (const int*)d_in[4];
    const float* gt_bboxes     = (const float*)d_in[5];
    const float* gt_poses      = (const float*)d_in[6];
    const float* pad_gt_mask   = (const float*)d_in[7];
    const int*   bg_ptr        = (const int*)d_in[8];

    char* ws = (char*)d_ws;
    unsigned* cells         = (unsigned*)(ws + WS_CELLS);
    unsigned* rowmax_metric = (unsigned*)(ws + WS_RM);
    unsigned* rowmax_iou    = (unsigned*)(ws + WS_RI);
    int*      assigned      = (int*)(ws + WS_ASSIGNED);
    int*      bin_start     = (int*)(ws + WS_BINSTART);
    int*      bin_id        = (int*)(ws + WS_BINID);
    float2*   bin_xy        = (float2*)(ws + WS_BINXY);

    prep_kernel<<<CLRB + 1, 256, 0, stream>>>(anchor_points, ws);

    topk_kernel<<<BB * NGT, 64, 0, stream>>>(
        pred_scores, pred_bboxes, anchor_points, gt_labels, gt_bboxes, pad_gt_mask,
        bin_start, bin_id, bin_xy, cells);

    dim3 gridBL((LL + 255) / 256, BB);
    decode_kernel<<<gridBL, 256, 0, stream>>>(
        pred_scores, pred_bboxes, gt_labels, gt_bboxes, cells,
        assigned, rowmax_metric, rowmax_iou);

    const int TOT4 = BB * LL * KPT * 3 / 4;
    int pose_blocks = (TOT4 + 255) / 256;              // 13,388
    write_pose_kernel<<<1056 + pose_blocks, 256, 0, stream>>>(
        pred_scores, pred_bboxes, gt_labels, gt_bboxes, gt_poses,
        assigned, rowmax_metric, rowmax_iou, bg_ptr, (float*)d_out);
}

// Round 14
// 88.593 us; speedup vs baseline: 1.0966x; 1.0966x over previous
//
#include <hip/hip_runtime.h>
#include <hip/hip_bf16.h>

#define BB    32
#define LL    8400
#define NGT   64
#define CCH   1
#define KPT   17
#define NTOPK 13
#define POOL  1024
#define NBIN  32           // 32x32 bins over [0,640], bin width 20 -> *0.05f

// f32-element chunk offsets (return order: labels, bboxes, poses, scores, gt_index)
#define OFF_LAB  ((size_t)0)
#define OFF_BOX  ((size_t)268800)
#define OFF_POSE ((size_t)1344000)
#define OFF_SC   ((size_t)15052800)
#define OFF_GI   ((size_t)15321600)

// workspace layout (bytes)
#define WS_CELLS    0
#define WS_RM       1075200
#define WS_RI       1083392
#define WS_ASSIGNED 1091584
#define WS_BINCNT   2166784     // 1024 ints (4096 B)
#define WS_BINSTART 2170880     // 1025 ints (4100 B, pad to 4104)
#define WS_BINCUR   2174984     // 1024 ints (4096 B)
#define WS_BINID    2179080     // 8400 ints (33600 B)
#define WS_BINXY    2212680     // 8400 float2 (67200 B), 8B-aligned

// ---------- helpers (fp contract OFF to match the CPU reference op order) ----------

__device__ __forceinline__ float iou_pair(float gx1, float gy1, float gx2, float gy2,
                                          float px1, float py1, float px2, float py2)
{
#pragma clang fp contract(off)
    float ltx = fmaxf(gx1, px1);
    float lty = fmaxf(gy1, py1);
    float rbx = fminf(gx2, px2);
    float rby = fminf(gy2, py2);
    float w = fmaxf(rbx - ltx, 0.0f);
    float h = fmaxf(rby - lty, 0.0f);
    float inter = w * h;
    float ag = (gx2 - gx1) * (gy2 - gy1);
    float ap = (px2 - px1) * (py2 - py1);
    return inter / (ag + ap - inter + 1e-9f);
}

__device__ __forceinline__ bool in_box(float ax, float ay,
                                       float gx1, float gy1, float gx2, float gy2)
{
#pragma clang fp contract(off)
    float m = fminf(fminf(ax - gx1, ay - gy1), fminf(gx2 - ax, gy2 - ay));
    return m > 1e-9f;
}

__device__ __forceinline__ float pow6(float x)
{
#pragma clang fp contract(off)
    float x2 = x * x;
    return (x2 * x2) * x2;
}

__device__ __forceinline__ int bin_of(float x)
{
    int v = (int)floorf(x * 0.05f);        // monotone in x
    return v < 0 ? 0 : (v > NBIN - 1 ? NBIN - 1 : v);
}

// ---------- K_clear: zero cells + rowmax (1,091,584 B) and bin_cnt (4,096 B) ----------

__global__ __launch_bounds__(256) void clear_kernel(char* __restrict__ ws)
{
    const int N4A = 1091584 / 16;          // 68,224
    const int N4B = 4096 / 16;             // 256
    int t = blockIdx.x * 256 + threadIdx.x;
    if (t < N4A)
        reinterpret_cast<float4*>(ws + WS_CELLS)[t] = make_float4(0.f, 0.f, 0.f, 0.f);
    else if (t < N4A + N4B)
        reinterpret_cast<float4*>(ws + WS_BINCNT)[t - N4A] = make_float4(0.f, 0.f, 0.f, 0.f);
}

// ---------- binning: count (full grid) -> scan (1 block) -> scatter (full grid) ----------

__global__ __launch_bounds__(256) void count_kernel(
    const float* __restrict__ anchor_points, int* __restrict__ bin_cnt)
{
    int l = blockIdx.x * 256 + threadIdx.x;
    if (l >= LL) return;
    float2 ap = reinterpret_cast<const float2*>(anchor_points)[l];
    atomicAdd(&bin_cnt[bin_of(ap.y) * NBIN + bin_of(ap.x)], 1);
}

__global__ __launch_bounds__(1024) void scan_kernel(
    const int* __restrict__ bin_cnt,
    int* __restrict__ bin_start, int* __restrict__ bin_cursor)
{
    __shared__ int off[NBIN * NBIN];
    int tid = threadIdx.x;
    off[tid] = bin_cnt[tid];
    __syncthreads();
    for (int s = 1; s < NBIN * NBIN; s <<= 1) {
        int v = (tid >= s) ? off[tid - s] : 0;
        __syncthreads();
        off[tid] += v;
        __syncthreads();
    }
    bin_start[tid + 1] = off[tid];
    int excl = (tid == 0) ? 0 : off[tid - 1];
    bin_cursor[tid] = excl;
    if (tid == 0) bin_start[0] = 0;
}

__global__ __launch_bounds__(256) void scatter_kernel(
    const float* __restrict__ anchor_points,
    int* __restrict__ bin_cursor,
    int* __restrict__ bin_id, float2* __restrict__ bin_xy)
{
    int l = blockIdx.x * 256 + threadIdx.x;
    if (l >= LL) return;
    float2 ap = reinterpret_cast<const float2*>(anchor_points)[l];
    int bin = bin_of(ap.y) * NBIN + bin_of(ap.x);
    int slot = atomicAdd(&bin_cursor[bin], 1);
    bin_id[slot] = l;
    bin_xy[slot] = ap;
}

// ---------- K1: single-wave binned candidate-pool exact top-13 ----------
// key = (value_bits << 32) | (0xFFFFFFFF - l)  -> order = (value desc, index asc),
// exactly lax.top_k's tie semantics; keys unique. Pool = {in-box anchors, full
// metric} U {l<26 out-of-box, v=0}: provably contains the reference's top-13.

__global__ __launch_bounds__(64) void topk_kernel(
    const float* __restrict__ pred_scores,
    const float* __restrict__ pred_bboxes,
    const float* __restrict__ anchor_points,
    const int*   __restrict__ gt_labels,
    const float* __restrict__ gt_bboxes,
    const float* __restrict__ pad_gt_mask,
    const int*   __restrict__ bin_start,
    const int*   __restrict__ bin_id,
    const float2* __restrict__ bin_xy,
    unsigned*    __restrict__ cells)
{
    __shared__ unsigned long long pool[POOL];          // 8,192 B
    __shared__ int cnt;

    int b = blockIdx.x >> 6;
    int i = blockIdx.x & 63;
    if (pad_gt_mask[b * NGT + i] == 0.0f) return;   // padded row (uniform exit)

    int lane = threadIdx.x;
    if (lane == 0) cnt = 0;
    __syncthreads();

    int gbase = (b * NGT + i) * 4;
    float gx1 = gt_bboxes[gbase + 0];
    float gy1 = gt_bboxes[gbase + 1];
    float gx2 = gt_bboxes[gbase + 2];
    float gy2 = gt_bboxes[gbase + 3];
    int lbl = gt_labels[b * NGT + i];

    // pre-pass: zero-metric fallback candidates l<26 (out-of-box only; in-box
    // l<26 anchors are found by the bin scan with their true metric)
    if (lane < 2 * NTOPK) {
        float2 ap = reinterpret_cast<const float2*>(anchor_points)[lane];
        if (!in_box(ap.x, ap.y, gx1, gy1, gx2, gy2)) {
            int slot = atomicAdd(&cnt, 1);
            pool[slot] = (unsigned long long)(0xFFFFFFFFu - (unsigned)lane);  // v=0
        }
    }

    // bin-rect scan: per by-row, bins bx0..bx1 form one contiguous slot range
    int bx0 = bin_of(gx1), bx1 = bin_of(gx2);
    int by0 = bin_of(gy1), by1 = bin_of(gy2);
    for (int by = by0; by <= by1; ++by) {
        int s = bin_start[by * NBIN + bx0];
        int e = bin_start[by * NBIN + bx1 + 1];
        for (int t = s + lane; t < e; t += 64) {
            float2 ap = bin_xy[t];
            if (in_box(ap.x, ap.y, gx1, gy1, gx2, gy2)) {
                int l = bin_id[t];
                int pidx = b * LL + l;
                float4 pb = reinterpret_cast<const float4*>(pred_bboxes)[pidx];
                float iou = iou_pair(gx1, gy1, gx2, gy2, pb.x, pb.y, pb.z, pb.w);
                float score = pred_scores[pidx * CCH + lbl];
                float v = score * pow6(iou);            // >= 0
                int slot = atomicAdd(&cnt, 1);
                if (slot < POOL) {
                    pool[slot] =
                        ((unsigned long long)__float_as_uint(v) << 32) |
                        (unsigned long long)(0xFFFFFFFFu - (unsigned)l);
                }
            }
        }
    }
    __syncthreads();

    int total = cnt;
    unsigned long long winner = 0;         // lane k holds round-k winner
    if (total <= POOL) {
        // 13-round wave argmax extraction; winner parks in lane k's register
#pragma unroll
        for (int k = 0; k < NTOPK; ++k) {
            unsigned long long lm = 0;
            int li = -1;
            for (int e = lane; e < total; e += 64) {
                unsigned long long pv = pool[e];
                if (pv > lm) { lm = pv; li = e; }
            }
            unsigned long long m = lm;
#pragma unroll
            for (int off = 32; off > 0; off >>= 1) {
                unsigned long long o = __shfl_xor(m, off);
                m = o > m ? o : m;
            }
            if (lane == k) winner = m;
            if (li >= 0 && lm == m) pool[li] = 0;   // consume (unique key -> one lane)
        }
    } else {
        // overflow fallback (unreachable on this data): threshold-descend full rescan
        unsigned long long prev = ~0ull;
#pragma unroll 1
        for (int k = 0; k < NTOPK; ++k) {
            unsigned long long lm = 0;
            for (int l = lane; l < LL; l += 64) {
                int pidx = b * LL + l;
                float4 pb = reinterpret_cast<const float4*>(pred_bboxes)[pidx];
                float iou = iou_pair(gx1, gy1, gx2, gy2, pb.x, pb.y, pb.z, pb.w);
                float score = pred_scores[pidx * CCH + lbl];
                float metric = score * pow6(iou);
                float2 ap = reinterpret_cast<const float2*>(anchor_points)[l];
                float v = in_box(ap.x, ap.y, gx1, gy1, gx2, gy2) ? metric : 0.0f;
                unsigned long long key =
                    ((unsigned long long)__float_as_uint(v) << 32) |
                    (unsigned long long)(0xFFFFFFFFu - (unsigned)l);
                if (key < prev && key > lm) lm = key;
            }
            unsigned long long m = lm;
#pragma unroll
            for (int off = 32; off > 0; off >>= 1) {
                unsigned long long o = __shfl_xor(m, off);
                m = o > m ? o : m;
            }
            if (lane == k) winner = m;
            prev = m;
        }
    }

    // parallel emit: lanes 0..12 process their winner concurrently
    if (lane < NTOPK && winner != 0ull) {
        unsigned lw = 0xFFFFFFFFu - (unsigned)(winner & 0xFFFFFFFFull);
        float v = __uint_as_float((unsigned)(winner >> 32));
        bool posw;
        if (v > 0.0f) {
            posw = true;                   // metric>0 implies in_gts
        } else {
            float2 ap = reinterpret_cast<const float2*>(anchor_points)[lw];
            posw = in_box(ap.x, ap.y, gx1, gy1, gx2, gy2);
        }
        if (posw)
            atomicAdd(&cells[b * LL + lw], 1u + ((unsigned)i << 8));
    }
}

// ---------- K2: decode cell -> assigned gt (or -1) + row maxima of metric/iou ----------

__global__ __launch_bounds__(256) void decode_kernel(
    const float* __restrict__ pred_scores,
    const float* __restrict__ pred_bboxes,
    const int*   __restrict__ gt_labels,
    const float* __restrict__ gt_bboxes,
    const unsigned* __restrict__ cells,
    int*      __restrict__ assigned,
    unsigned* __restrict__ rowmax_metric,
    unsigned* __restrict__ rowmax_iou)
{
    __shared__ float gsh[NGT * 4];
    int b = blockIdx.y;
    int tid = threadIdx.x;
    for (int k = tid; k < NGT * 4; k += 256) gsh[k] = gt_bboxes[b * NGT * 4 + k];
    __syncthreads();

    int l = blockIdx.x * 256 + tid;
    if (l >= LL) return;
    int idx = b * LL + l;

    unsigned cell = cells[idx];
    int cnt = (int)(cell & 0xFFu);
    if (cnt == 0) { assigned[idx] = -1; return; }

    float px1 = pred_bboxes[idx * 4 + 0];
    float py1 = pred_bboxes[idx * 4 + 1];
    float px2 = pred_bboxes[idx * 4 + 2];
    float py2 = pred_bboxes[idx * 4 + 3];

    int istar;
    if (cnt == 1) {
        int v = (int)(cell >> 8);
        istar = (v >= 0 && v < NGT) ? v : 0;
    } else {
        // reference substitutes is_max_iou over ALL 64 gts (incl. padded), first-max tie
        float best = -1.0f;
        int bi = 0;
        for (int i = 0; i < NGT; ++i) {
            float iou = iou_pair(gsh[i * 4 + 0], gsh[i * 4 + 1], gsh[i * 4 + 2], gsh[i * 4 + 3],
                                 px1, py1, px2, py2);
            if (iou > best) { best = iou; bi = i; }
        }
        istar = bi;
    }
    assigned[idx] = istar;

    float iou = iou_pair(gsh[istar * 4 + 0], gsh[istar * 4 + 1], gsh[istar * 4 + 2], gsh[istar * 4 + 3],
                         px1, py1, px2, py2);
    int lbl = gt_labels[b * NGT + istar];
    float score = pred_scores[idx * CCH + lbl];
    float met = score * pow6(iou);
    atomicMax(&rowmax_metric[b * NGT + istar], __float_as_uint(met));  // values >= 0
    atomicMax(&rowmax_iou[b * NGT + istar], __float_as_uint(iou));
}

// ---------- K3: labels / bboxes / scores / gt_index (float32 stores) ----------

__global__ __launch_bounds__(256) void write_kernel(
    const float* __restrict__ pred_scores,
    const float* __restrict__ pred_bboxes,
    const int*   __restrict__ gt_labels,
    const float* __restrict__ gt_bboxes,
    const int*      __restrict__ assigned,
    const unsigned* __restrict__ rowmax_metric,
    const unsigned* __restrict__ rowmax_iou,
    const int*   __restrict__ bg_ptr,
    float* __restrict__ out)
{
    __shared__ float gsh[NGT * 4];
    int b = blockIdx.y;
    int tid = threadIdx.x;
    for (int k = tid; k < NGT * 4; k += 256) gsh[k] = gt_bboxes[b * NGT * 4 + k];
    __syncthreads();

    int l = blockIdx.x * 256 + tid;
    if (l >= LL) return;
    int idx = b * LL + l;

    int a = assigned[idx];
    bool pos = a >= 0;
    int agi = pos ? a : 0;                 // argmax of all-zero column == 0
    int bg = *bg_ptr;
    int lbl = pos ? gt_labels[b * NGT + agi] : bg;

    out[OFF_LAB + (size_t)idx] = (float)lbl;
    out[OFF_GI + (size_t)idx]  = (float)(b * NGT + agi);

    float4 box;
    box.x = gsh[agi * 4 + 0];
    box.y = gsh[agi * 4 + 1];
    box.z = gsh[agi * 4 + 2];
    box.w = gsh[agi * 4 + 3];
    reinterpret_cast<float4*>(out + OFF_BOX)[idx] = box;

    float am = 0.0f;
    if (pos) {
        float px1 = pred_bboxes[idx * 4 + 0];
        float py1 = pred_bboxes[idx * 4 + 1];
        float px2 = pred_bboxes[idx * 4 + 2];
        float py2 = pred_bboxes[idx * 4 + 3];
        float iou = iou_pair(box.x, box.y, box.z, box.w, px1, py1, px2, py2);
        float score = pred_scores[idx * CCH + gt_labels[b * NGT + a]];
        float met = score * pow6(iou);
        float mm = __uint_as_float(rowmax_metric[b * NGT + a]);
        float mi = __uint_as_float(rowmax_iou[b * NGT + a]);
        am = met / (mm + 1e-9f) * mi;
    }
    int kc = (bg == 0) ? 1 : 0;            // kept class column (C==1)
    out[OFF_SC + (size_t)idx] = (lbl == kc) ? am : 0.0f;
}

// ---------- K4: poses, float4-chunked gather (16B coalesced stores) ----------

__global__ __launch_bounds__(256) void pose_kernel(
    const float* __restrict__ gt_poses,
    const int*   __restrict__ assigned,
    float* __restrict__ out_poses)
{
    const int TOT4 = BB * LL * KPT * 3 / 4;     // 3,427,200
    int c = blockIdx.x * 256 + threadIdx.x;
    if (c >= TOT4) return;
    int e0 = c * 4;
    float r[4];
#pragma unroll
    for (int u = 0; u < 4; ++u) {
        int e = e0 + u;
        int anchor = e / (KPT * 3);             // const-div -> magic mul
        int j = e - anchor * (KPT * 3);
        int b = anchor / LL;
        int a = assigned[anchor];
        int agi = a >= 0 ? a : 0;
        r[u] = gt_poses[(size_t)(b * NGT + agi) * (KPT * 3) + j];
    }
    float4 v;
    v.x = r[0]; v.y = r[1]; v.z = r[2]; v.w = r[3];
    reinterpret_cast<float4*>(out_poses)[c] = v;   // OFF_POSE*4 bytes is 16B-aligned
}

// ---------- launch ----------

extern "C" void kernel_launch(void* const* d_in, const int* in_sizes, int n_in,
                              void* d_out, int out_size, void* d_ws, size_t ws_size,
                              hipStream_t stream)
{
    const float* pred_scores   = (const float*)d_in[0];
    const float* pred_bboxes   = (const float*)d_in[1];
    // d_in[2] = pred_poses: unused by the reference computation
    const float* anchor_points = (const float*)d_in[3];
    const int*   gt_labels     = (const int*)d_in[4];
    const float* gt_bboxes     = (const float*)d_in[5];
    const float* gt_poses      = (const float*)d_in[6];
    const float* pad_gt_mask   = (const float*)d_in[7];
    const int*   bg_ptr        = (const int*)d_in[8];

    char* ws = (char*)d_ws;
    unsigned* cells         = (unsigned*)(ws + WS_CELLS);
    unsigned* rowmax_metric = (unsigned*)(ws + WS_RM);
    unsigned* rowmax_iou    = (unsigned*)(ws + WS_RI);
    int*      assigned      = (int*)(ws + WS_ASSIGNED);
    int*      bin_cnt       = (int*)(ws + WS_BINCNT);
    int*      bin_start     = (int*)(ws + WS_BINSTART);
    int*      bin_cursor    = (int*)(ws + WS_BINCUR);
    int*      bin_id        = (int*)(ws + WS_BINID);
    float2*   bin_xy        = (float2*)(ws + WS_BINXY);

    const int NCLR = (1091584 + 4096) / 16;
    clear_kernel<<<(NCLR + 255) / 256, 256, 0, stream>>>(ws);

    int ablocks = (LL + 255) / 256;
    count_kernel<<<ablocks, 256, 0, stream>>>(anchor_points, bin_cnt);
    scan_kernel<<<1, 1024, 0, stream>>>(bin_cnt, bin_start, bin_cursor);
    scatter_kernel<<<ablocks, 256, 0, stream>>>(anchor_points, bin_cursor, bin_id, bin_xy);

    topk_kernel<<<BB * NGT, 64, 0, stream>>>(
        pred_scores, pred_bboxes, anchor_points, gt_labels, gt_bboxes, pad_gt_mask,
        bin_start, bin_id, bin_xy, cells);

    dim3 gridBL((LL + 255) / 256, BB);
    decode_kernel<<<gridBL, 256, 0, stream>>>(
        pred_scores, pred_bboxes, gt_labels, gt_bboxes, cells,
        assigned, rowmax_metric, rowmax_iou);

    write_kernel<<<gridBL, 256, 0, stream>>>(
        pred_scores, pred_bboxes, gt_labels, gt_bboxes,
        assigned, rowmax_metric, rowmax_iou, bg_ptr, (float*)d_out);

    const int TOT4 = BB * LL * KPT * 3 / 4;
    pose_kernel<<<(TOT4 + 255) / 256, 256, 0, stream>>>(
        gt_poses, assigned, (float*)d_out + OFF_POSE);
}